// Round 2
// baseline (3439.196 us; speedup 1.0000x reference)
//
#include <hip/hip_runtime.h>
#include <stdint.h>

#define BLK 256

static constexpr float F_EPS = 1e-7f;   // GENConv message eps
static constexpr float F_NEG = 0.01f;   // LeakyReLU slope
static constexpr int   TOPK  = 512;

__device__ __forceinline__ unsigned int ord_f32(float f) {
  unsigned int u = __float_as_uint(f);
  return (u & 0x80000000u) ? ~u : (u | 0x80000000u);
}

// ---------------- dense: out[n,COUT] = in[n,CIN] @ W + b ----------------
template<int CIN, int COUT>
__global__ __launch_bounds__(BLK) void lin_kernel(const float* __restrict__ in,
    const float* __restrict__ W, const float* __restrict__ b,
    float* __restrict__ out, int n) {
  __shared__ __align__(16) float sW[CIN * COUT];
  __shared__ float sB[COUT];
  for (int i = threadIdx.x; i < CIN * COUT; i += BLK) sW[i] = W[i];
  for (int i = threadIdx.x; i < COUT; i += BLK) sB[i] = b[i];
  __syncthreads();
  int node = blockIdx.x * BLK + threadIdx.x;
  if (node >= n) return;
  float x[CIN];
  if constexpr ((CIN & 3) == 0) {
    const float4* row = reinterpret_cast<const float4*>(in + (size_t)node * CIN);
    #pragma unroll
    for (int k4 = 0; k4 < CIN / 4; ++k4) {
      float4 v = row[k4];
      x[4*k4+0] = v.x; x[4*k4+1] = v.y; x[4*k4+2] = v.z; x[4*k4+3] = v.w;
    }
  } else {
    #pragma unroll
    for (int k = 0; k < CIN; ++k) x[k] = in[(size_t)node * CIN + k];
  }
  float* orow = out + (size_t)node * COUT;
  for (int j = 0; j < COUT; j += 4) {
    float a0 = sB[j], a1 = sB[j+1], a2 = sB[j+2], a3 = sB[j+3];
    #pragma unroll
    for (int k = 0; k < CIN; ++k) {
      const float4 w = *reinterpret_cast<const float4*>(&sW[k * COUT + j]);
      a0 += x[k] * w.x; a1 += x[k] * w.y; a2 += x[k] * w.z; a3 += x[k] * w.w;
    }
    float4 r; r.x = a0; r.y = a1; r.z = a2; r.w = a3;
    *reinterpret_cast<float4*>(orow + j) = r;
  }
}

// ---- MLP second half: t=relu(h*scale+shift); out=leaky(t@W+b) ----
template<int CIN, int COUT>
__global__ __launch_bounds__(BLK) void mlp2_kernel(const float* __restrict__ h,
    const float* __restrict__ scale, const float* __restrict__ shift,
    const float* __restrict__ W, const float* __restrict__ b,
    float* __restrict__ out, int n) {
  __shared__ __align__(16) float sW[CIN * COUT];
  __shared__ float sB[COUT];
  __shared__ float sSc[CIN];
  __shared__ float sSh[CIN];
  for (int i = threadIdx.x; i < CIN * COUT; i += BLK) sW[i] = W[i];
  for (int i = threadIdx.x; i < COUT; i += BLK) sB[i] = b[i];
  for (int i = threadIdx.x; i < CIN; i += BLK) { sSc[i] = scale[i]; sSh[i] = shift[i]; }
  __syncthreads();
  int node = blockIdx.x * BLK + threadIdx.x;
  if (node >= n) return;
  float t[CIN];
  const float4* row = reinterpret_cast<const float4*>(h + (size_t)node * CIN);
  #pragma unroll
  for (int k4 = 0; k4 < CIN / 4; ++k4) {
    float4 v = row[k4];
    t[4*k4+0] = fmaxf(v.x * sSc[4*k4+0] + sSh[4*k4+0], 0.f);
    t[4*k4+1] = fmaxf(v.y * sSc[4*k4+1] + sSh[4*k4+1], 0.f);
    t[4*k4+2] = fmaxf(v.z * sSc[4*k4+2] + sSh[4*k4+2], 0.f);
    t[4*k4+3] = fmaxf(v.w * sSc[4*k4+3] + sSh[4*k4+3], 0.f);
  }
  float* orow = out + (size_t)node * COUT;
  for (int j = 0; j < COUT; j += 4) {
    float a0 = sB[j], a1 = sB[j+1], a2 = sB[j+2], a3 = sB[j+3];
    #pragma unroll
    for (int k = 0; k < CIN; ++k) {
      const float4 w = *reinterpret_cast<const float4*>(&sW[k * COUT + j]);
      a0 += t[k] * w.x; a1 += t[k] * w.y; a2 += t[k] * w.z; a3 += t[k] * w.w;
    }
    a0 = a0 > 0.f ? a0 : F_NEG * a0;
    a1 = a1 > 0.f ? a1 : F_NEG * a1;
    a2 = a2 > 0.f ? a2 : F_NEG * a2;
    a3 = a3 > 0.f ? a3 : F_NEG * a3;
    float4 r; r.x = a0; r.y = a1; r.z = a2; r.w = a3;
    *reinterpret_cast<float4*>(orow + j) = r;
  }
}

// ---- per-edge softmax-agg accumulation (no max pass; exp(msg) directly) ----
template<int C>
__global__ __launch_bounds__(BLK) void edge_kernel(const int* __restrict__ src,
    const int* __restrict__ dst, const float* __restrict__ x,
    float* __restrict__ den, float* __restrict__ num, int E) {
  constexpr int GP = C / 4;
  int idx = blockIdx.x * BLK + threadIdx.x;
  if (idx >= E * GP) return;
  int e = idx / GP;
  int c = (idx - e * GP) * 4;
  int s = src[e], d = dst[e];
  float4 xv = *reinterpret_cast<const float4*>(x + (size_t)s * C + c);
  float m0 = fmaxf(xv.x, 0.f) + F_EPS;
  float m1 = fmaxf(xv.y, 0.f) + F_EPS;
  float m2 = fmaxf(xv.z, 0.f) + F_EPS;
  float m3 = fmaxf(xv.w, 0.f) + F_EPS;
  float a0 = expf(m0), a1 = expf(m1), a2 = expf(m2), a3 = expf(m3);
  float* dp = den + (size_t)d * C + c;
  float* np = num + (size_t)d * C + c;
  atomicAdd(dp + 0, a0); atomicAdd(dp + 1, a1);
  atomicAdd(dp + 2, a2); atomicAdd(dp + 3, a3);
  atomicAdd(np + 0, m0 * a0); atomicAdd(np + 1, m1 * a1);
  atomicAdd(np + 2, m2 * a2); atomicAdd(np + 3, m3 * a3);
}

// ---- res = num/(den+1e-16) + x, in place into num ----
__global__ __launch_bounds__(BLK) void resid_kernel(float* __restrict__ num,
    const float* __restrict__ den, const float* __restrict__ x, int total4) {
  int i = blockIdx.x * BLK + threadIdx.x;
  if (i >= total4) return;
  float4 nv = reinterpret_cast<float4*>(num)[i];
  float4 dv = reinterpret_cast<const float4*>(den)[i];
  float4 xv = reinterpret_cast<const float4*>(x)[i];
  float4 r;
  r.x = nv.x / (dv.x + 1e-16f) + xv.x;
  r.y = nv.y / (dv.y + 1e-16f) + xv.y;
  r.z = nv.z / (dv.z + 1e-16f) + xv.z;
  r.w = nv.w / (dv.w + 1e-16f) + xv.w;
  reinterpret_cast<float4*>(num)[i] = r;
}

// ---- column sums for BN stats (FP64 accumulation to avoid cancellation) ----
template<int COUT>
__global__ __launch_bounds__(BLK) void stat_kernel(const float* __restrict__ h,
    double* __restrict__ gsum, double* __restrict__ gsq, int n) {
  constexpr int G = COUT / 4;      // channel groups (float4)
  constexpr int REPS = BLK / G;
  double s0 = 0, s1 = 0, s2 = 0, s3 = 0, q0 = 0, q1 = 0, q2 = 0, q3 = 0;
  int total4 = n * G;
  for (int i = blockIdx.x * BLK + threadIdx.x; i < total4; i += gridDim.x * BLK) {
    float4 v = reinterpret_cast<const float4*>(h)[i];
    double dx = v.x, dy = v.y, dz = v.z, dw = v.w;
    s0 += dx; q0 += dx * dx;
    s1 += dy; q1 += dy * dy;
    s2 += dz; q2 += dz * dz;
    s3 += dw; q3 += dw * dw;
  }
  __shared__ double sL[BLK * 8];
  double* my = sL + threadIdx.x * 8;
  my[0] = s0; my[1] = s1; my[2] = s2; my[3] = s3;
  my[4] = q0; my[5] = q1; my[6] = q2; my[7] = q3;
  __syncthreads();
  int g = threadIdx.x;
  if (g < G) {
    for (int r = 1; r < REPS; ++r) {
      double* o = sL + (g + r * G) * 8;
      s0 += o[0]; s1 += o[1]; s2 += o[2]; s3 += o[3];
      q0 += o[4]; q1 += o[5]; q2 += o[6]; q3 += o[7];
    }
    atomicAdd(&gsum[4*g+0], s0); atomicAdd(&gsum[4*g+1], s1);
    atomicAdd(&gsum[4*g+2], s2); atomicAdd(&gsum[4*g+3], s3);
    atomicAdd(&gsq[4*g+0], q0); atomicAdd(&gsq[4*g+1], q1);
    atomicAdd(&gsq[4*g+2], q2); atomicAdd(&gsq[4*g+3], q3);
  }
}

__global__ void bn_fin(const double* __restrict__ sum, const double* __restrict__ sq,
                       const float* __restrict__ g, const float* __restrict__ be,
                       float* __restrict__ sc, float* __restrict__ sh, int H, int n) {
  int j = threadIdx.x;
  if (j >= H) return;
  double inv_n = 1.0 / (double)n;
  double mu = sum[j] * inv_n;
  double var = sq[j] * inv_n - mu * mu;
  double s = (double)g[j] / sqrt(var + 1e-5);
  sc[j] = (float)s;
  sh[j] = (float)((double)be[j] - mu * s);
}

__global__ void norm_kernel(const float* __restrict__ w, float* __restrict__ invn) {
  float v = w[threadIdx.x];
  float sq = v * v;
  for (int off = 32; off; off >>= 1) sq += __shfl_down(sq, off);
  if (threadIdx.x == 0) invn[0] = 1.f / sqrtf(sq);
}

__global__ __launch_bounds__(BLK) void score_kernel(const float* __restrict__ x,
    const float* __restrict__ w, const float* __restrict__ invn,
    float* __restrict__ scores, unsigned long long* __restrict__ keys, int n) {
  __shared__ float sw[64];
  if (threadIdx.x < 64) sw[threadIdx.x] = w[threadIdx.x];
  __syncthreads();
  int node = blockIdx.x * BLK + threadIdx.x;
  if (node >= n) return;
  const float4* row = reinterpret_cast<const float4*>(x + (size_t)node * 64);
  float acc = 0.f;
  #pragma unroll
  for (int k4 = 0; k4 < 16; ++k4) {
    float4 v = row[k4];
    const float4 wv = *reinterpret_cast<const float4*>(&sw[4 * k4]);
    acc += v.x * wv.x + v.y * wv.y + v.z * wv.z + v.w * wv.w;
  }
  float s = tanhf(acc * invn[0]);
  scores[node] = s;
  keys[node] = ((unsigned long long)ord_f32(s) << 32) | (unsigned int)(~node);
}

// ---- radix-select state: istate[0]=k istate[1]=digit istate[2]=sel_count
//      istate[3]=cnt_buf0 istate[4]=cnt_buf1; hist[256] follows ----
__global__ void init_state(int* istate, int n) {
  if (threadIdx.x == 0) { istate[0] = TOPK; istate[3] = n; }
}

__global__ __launch_bounds__(BLK) void hist_kernel(const unsigned long long* __restrict__ keys,
    const int* __restrict__ istate, int* __restrict__ hist, int shift, int pin) {
  __shared__ int hl[256];
  hl[threadIdx.x] = 0;
  __syncthreads();
  int cnt = istate[3 + pin];
  int i = blockIdx.x * BLK + threadIdx.x;
  if (i < cnt) {
    int b = (int)((keys[i] >> shift) & 255ull);
    atomicAdd(&hl[b], 1);
  }
  __syncthreads();
  int v = hl[threadIdx.x];
  if (v) atomicAdd(&hist[threadIdx.x], v);
}

__global__ void pick_kernel(int* istate, int* hist, int pout) {
  if (threadIdx.x == 0) {
    int k = istate[0];
    int run = 0;
    for (int d = 255; d >= 0; --d) {
      int c = hist[d];
      if (run + c >= k) { istate[1] = d; istate[0] = k - run; break; }
      run += c;
    }
    istate[3 + pout] = 0;
  }
  __syncthreads();
  hist[threadIdx.x] = 0;
}

__global__ __launch_bounds__(BLK) void compact_kernel(const unsigned long long* __restrict__ in,
    unsigned long long* __restrict__ outb, unsigned long long* __restrict__ sel,
    int* __restrict__ istate, int shift, int pin, int pout) {
  int cnt = istate[3 + pin];
  int i = blockIdx.x * BLK + threadIdx.x;
  if (i >= cnt) return;
  unsigned long long kkey = in[i];
  int b = (int)((kkey >> shift) & 255ull);
  int digit = istate[1];
  if (b > digit) {
    int p = atomicAdd(&istate[2], 1);
    sel[p] = kkey;
  } else if (b == digit) {
    int p = atomicAdd(&istate[3 + pout], 1);
    outb[p] = kkey;
  }
}

__global__ void append_kernel(const unsigned long long* __restrict__ in,
                              unsigned long long* __restrict__ sel, int* istate) {
  int k = istate[0];
  for (int i = threadIdx.x; i < k; i += blockDim.x) {
    int p = atomicAdd(&istate[2], 1);
    sel[p] = in[i];
  }
}

__global__ __launch_bounds__(512) void sort_gather(const unsigned long long* __restrict__ sel,
    const float* __restrict__ scores, const float* __restrict__ x, float* __restrict__ out) {
  __shared__ unsigned long long sk[512];
  int t = threadIdx.x;
  sk[t] = sel[t];
  __syncthreads();
  for (int k = 2; k <= 512; k <<= 1) {
    for (int j = k >> 1; j > 0; j >>= 1) {
      int ixj = t ^ j;
      if (ixj > t) {
        bool dirDesc = ((t & k) == 0);
        unsigned long long A = sk[t], B = sk[ixj];
        bool swp = dirDesc ? (A < B) : (A > B);
        if (swp) { sk[t] = B; sk[ixj] = A; }
      }
      __syncthreads();
    }
  }
  unsigned long long kk = sk[t];
  int n = (int)(~(unsigned int)(kk & 0xffffffffull));
  float v = scores[n];
  const float4* row = reinterpret_cast<const float4*>(x + (size_t)n * 64);
  float4* orow = reinterpret_cast<float4*>(out + (size_t)t * 64);
  #pragma unroll
  for (int c = 0; c < 16; ++c) {
    float4 r = row[c];
    r.x *= v; r.y *= v; r.z *= v; r.w *= v;
    orow[c] = r;
  }
}

extern "C" void kernel_launch(void* const* d_in, const int* in_sizes, int n_in,
                              void* d_out, int out_size, void* d_ws, size_t ws_size,
                              hipStream_t stream) {
  const int N = in_sizes[0] / 3;
  const int E = in_sizes[1] / 2;

  const float* pos   = (const float*)d_in[0];
  const int*   ei    = (const int*)d_in[1];
  const int*   src   = ei;
  const int*   dst   = ei + E;
  const float* c1_lw = (const float*)d_in[2];
  const float* c1_lb = (const float*)d_in[3];
  const float* c1_w1 = (const float*)d_in[4];
  const float* c1_b1 = (const float*)d_in[5];
  const float* c1_g1 = (const float*)d_in[6];
  const float* c1_be1= (const float*)d_in[7];
  const float* c1_w2 = (const float*)d_in[8];
  const float* c1_b2 = (const float*)d_in[9];
  const float* c2_lw = (const float*)d_in[10];
  const float* c2_lb = (const float*)d_in[11];
  const float* c2_w1 = (const float*)d_in[12];
  const float* c2_b1 = (const float*)d_in[13];
  const float* c2_g1 = (const float*)d_in[14];
  const float* c2_be1= (const float*)d_in[15];
  const float* c2_w2 = (const float*)d_in[16];
  const float* c2_b2 = (const float*)d_in[17];
  const float* poolw = (const float*)d_in[18];

  float* ws = (float*)d_ws;
  // conv1 region (reused by conv2):
  float* x1   = ws;                        // N*16
  float* den1 = ws + (size_t)16 * N;       // N*16
  float* num1 = ws + (size_t)32 * N;       // N*16 -> res1
  float* h1   = ws + (size_t)64 * N;       // N*32
  float* o1   = ws + (size_t)96 * N;       // N*16
  // conv2 region:
  float* x2   = ws;                        // N*64 (over x1/den1/num1, dead)
  float* den2 = ws + (size_t)64 * N;       // N*64 (over h1/o1, dead by then)
  float* num2 = ws + (size_t)128 * N;      // N*64 -> res2
  float* h2   = ws + (size_t)192 * N;      // N*128
  float* o2   = ws + (size_t)320 * N;      // N*64 final features
  float* scores = ws + (size_t)384 * N;    // N
  char* smallB = (char*)(ws + (size_t)385 * N);   // 8-byte aligned (N even)
  unsigned long long* candA = (unsigned long long*)smallB;   // N
  unsigned long long* candB = candA + N;                     // N
  unsigned long long* sel   = candB + N;                     // 512
  int* istate = (int*)(sel + TOPK);                          // 8 ints
  int* hist   = istate + 8;                                  // 256 ints
  double* dstat = (double*)(hist + 256);   // 8-aligned: (2N+512)*8 + 264*4 bytes from 8-aligned base
  double* sum1 = dstat;        double* sq1 = dstat + 32;
  double* sum2 = dstat + 64;   double* sq2 = dstat + 192;    // 128 each
  float* fbuf = (float*)(dstat + 320);
  float* sc1  = fbuf;        float* sh1 = fbuf + 32;
  float* sc2  = fbuf + 64;   float* sh2 = fbuf + 192;
  float* invn = fbuf + 320;

  const int nbN = (N + BLK - 1) / BLK;

  // zero accumulators + control state (every call: must be replay-safe)
  hipMemsetAsync(den1, 0, (size_t)32 * N * sizeof(float), stream);   // den1+num1
  hipMemsetAsync(istate, 0, 264 * sizeof(int) + 320 * sizeof(double) + 321 * sizeof(float), stream);

  // ---------------- conv1 ----------------
  lin_kernel<3, 16><<<nbN, BLK, 0, stream>>>(pos, c1_lw, c1_lb, x1, N);
  {
    int tot = E * 4;
    edge_kernel<16><<<(tot + BLK - 1) / BLK, BLK, 0, stream>>>(src, dst, x1, den1, num1, E);
  }
  {
    int total4 = N * 16 / 4;
    resid_kernel<<<(total4 + BLK - 1) / BLK, BLK, 0, stream>>>(num1, den1, x1, total4);
  }
  lin_kernel<16, 32><<<nbN, BLK, 0, stream>>>(num1, c1_w1, c1_b1, h1, N);
  stat_kernel<32><<<2048, BLK, 0, stream>>>(h1, sum1, sq1, N);
  bn_fin<<<1, 32, 0, stream>>>(sum1, sq1, c1_g1, c1_be1, sc1, sh1, 32, N);
  mlp2_kernel<32, 16><<<nbN, BLK, 0, stream>>>(h1, sc1, sh1, c1_w2, c1_b2, o1, N);

  // ---------------- conv2 ----------------
  lin_kernel<16, 64><<<nbN, BLK, 0, stream>>>(o1, c2_lw, c2_lb, x2, N);
  hipMemsetAsync(den2, 0, (size_t)128 * N * sizeof(float), stream);  // den2+num2
  {
    int tot = E * 16;
    edge_kernel<64><<<(tot + BLK - 1) / BLK, BLK, 0, stream>>>(src, dst, x2, den2, num2, E);
  }
  {
    int total4 = N * 64 / 4;
    resid_kernel<<<(total4 + BLK - 1) / BLK, BLK, 0, stream>>>(num2, den2, x2, total4);
  }
  lin_kernel<64, 128><<<nbN, BLK, 0, stream>>>(num2, c2_w1, c2_b1, h2, N);
  stat_kernel<128><<<2048, BLK, 0, stream>>>(h2, sum2, sq2, N);
  bn_fin<<<1, 128, 0, stream>>>(sum2, sq2, c2_g1, c2_be1, sc2, sh2, 128, N);
  mlp2_kernel<128, 64><<<nbN, BLK, 0, stream>>>(h2, sc2, sh2, c2_w2, c2_b2, o2, N);

  // ---------------- scores + exact top-K ----------------
  norm_kernel<<<1, 64, 0, stream>>>(poolw, invn);
  score_kernel<<<nbN, BLK, 0, stream>>>(o2, poolw, invn, scores, candA, N);
  init_state<<<1, 64, 0, stream>>>(istate, N);
  for (int round = 0; round < 8; ++round) {
    int shift = (7 - round) * 8;
    int pin = round & 1;
    int pout = pin ^ 1;
    const unsigned long long* bin = pin ? candB : candA;
    unsigned long long* bout = pout ? candB : candA;
    hist_kernel<<<nbN, BLK, 0, stream>>>(bin, istate, hist, shift, pin);
    pick_kernel<<<1, 256, 0, stream>>>(istate, hist, pout);
    compact_kernel<<<nbN, BLK, 0, stream>>>(bin, bout, sel, istate, shift, pin, pout);
  }
  append_kernel<<<1, 256, 0, stream>>>(candA, sel, istate);
  sort_gather<<<1, 512, 0, stream>>>(sel, scores, o2, (float*)d_out);

  (void)n_in; (void)out_size; (void)ws_size;
}

// Round 3
// 978.828 us; speedup vs baseline: 3.5136x; 3.5136x over previous
//
#include <hip/hip_runtime.h>
#include <stdint.h>

#define BLK 256

static constexpr float F_EPS = 1e-7f;   // GENConv message eps
static constexpr float F_NEG = 0.01f;   // LeakyReLU slope
static constexpr int   TOPK  = 512;

typedef unsigned long long u64;

__device__ __forceinline__ unsigned int ord_f32(float f) {
  unsigned int u = __float_as_uint(f);
  return (u & 0x80000000u) ? ~u : (u | 0x80000000u);
}

// ---------------- dense: out[n,COUT] = in[n,CIN] @ W + b ----------------
template<int CIN, int COUT>
__global__ __launch_bounds__(BLK) void lin_kernel(const float* __restrict__ in,
    const float* __restrict__ W, const float* __restrict__ b,
    float* __restrict__ out, int n) {
  __shared__ __align__(16) float sW[CIN * COUT];
  __shared__ float sB[COUT];
  for (int i = threadIdx.x; i < CIN * COUT; i += BLK) sW[i] = W[i];
  for (int i = threadIdx.x; i < COUT; i += BLK) sB[i] = b[i];
  __syncthreads();
  int node = blockIdx.x * BLK + threadIdx.x;
  if (node >= n) return;
  float x[CIN];
  if constexpr ((CIN & 3) == 0) {
    const float4* row = reinterpret_cast<const float4*>(in + (size_t)node * CIN);
    #pragma unroll
    for (int k4 = 0; k4 < CIN / 4; ++k4) {
      float4 v = row[k4];
      x[4*k4+0] = v.x; x[4*k4+1] = v.y; x[4*k4+2] = v.z; x[4*k4+3] = v.w;
    }
  } else {
    #pragma unroll
    for (int k = 0; k < CIN; ++k) x[k] = in[(size_t)node * CIN + k];
  }
  float* orow = out + (size_t)node * COUT;
  for (int j = 0; j < COUT; j += 4) {
    float a0 = sB[j], a1 = sB[j+1], a2 = sB[j+2], a3 = sB[j+3];
    #pragma unroll
    for (int k = 0; k < CIN; ++k) {
      const float4 w = *reinterpret_cast<const float4*>(&sW[k * COUT + j]);
      a0 += x[k] * w.x; a1 += x[k] * w.y; a2 += x[k] * w.z; a3 += x[k] * w.w;
    }
    float4 r; r.x = a0; r.y = a1; r.z = a2; r.w = a3;
    *reinterpret_cast<float4*>(orow + j) = r;
  }
}

// ---- MLP second half: t=relu(h*scale+shift); out=leaky(t@W+b) ----
template<int CIN, int COUT>
__global__ __launch_bounds__(BLK) void mlp2_kernel(const float* __restrict__ h,
    const float* __restrict__ scale, const float* __restrict__ shift,
    const float* __restrict__ W, const float* __restrict__ b,
    float* __restrict__ out, int n) {
  __shared__ __align__(16) float sW[CIN * COUT];
  __shared__ float sB[COUT];
  __shared__ float sSc[CIN];
  __shared__ float sSh[CIN];
  for (int i = threadIdx.x; i < CIN * COUT; i += BLK) sW[i] = W[i];
  for (int i = threadIdx.x; i < COUT; i += BLK) sB[i] = b[i];
  for (int i = threadIdx.x; i < CIN; i += BLK) { sSc[i] = scale[i]; sSh[i] = shift[i]; }
  __syncthreads();
  int node = blockIdx.x * BLK + threadIdx.x;
  if (node >= n) return;
  float t[CIN];
  const float4* row = reinterpret_cast<const float4*>(h + (size_t)node * CIN);
  #pragma unroll
  for (int k4 = 0; k4 < CIN / 4; ++k4) {
    float4 v = row[k4];
    t[4*k4+0] = fmaxf(v.x * sSc[4*k4+0] + sSh[4*k4+0], 0.f);
    t[4*k4+1] = fmaxf(v.y * sSc[4*k4+1] + sSh[4*k4+1], 0.f);
    t[4*k4+2] = fmaxf(v.z * sSc[4*k4+2] + sSh[4*k4+2], 0.f);
    t[4*k4+3] = fmaxf(v.w * sSc[4*k4+3] + sSh[4*k4+3], 0.f);
  }
  float* orow = out + (size_t)node * COUT;
  for (int j = 0; j < COUT; j += 4) {
    float a0 = sB[j], a1 = sB[j+1], a2 = sB[j+2], a3 = sB[j+3];
    #pragma unroll
    for (int k = 0; k < CIN; ++k) {
      const float4 w = *reinterpret_cast<const float4*>(&sW[k * COUT + j]);
      a0 += t[k] * w.x; a1 += t[k] * w.y; a2 += t[k] * w.z; a3 += t[k] * w.w;
    }
    a0 = a0 > 0.f ? a0 : F_NEG * a0;
    a1 = a1 > 0.f ? a1 : F_NEG * a1;
    a2 = a2 > 0.f ? a2 : F_NEG * a2;
    a3 = a3 > 0.f ? a3 : F_NEG * a3;
    float4 r; r.x = a0; r.y = a1; r.z = a2; r.w = a3;
    *reinterpret_cast<float4*>(orow + j) = r;
  }
}

// ---------------- CSR build ----------------
__global__ __launch_bounds__(BLK) void deg_kernel(const int* __restrict__ dst,
    int* __restrict__ deg, int E) {
  int e = blockIdx.x * BLK + threadIdx.x;
  if (e < E) atomicAdd(&deg[dst[e]], 1);
}

__global__ __launch_bounds__(BLK) void blocksum_kernel(const int* __restrict__ deg,
    int* __restrict__ bsum, int n) {
  int i = blockIdx.x * BLK + threadIdx.x;
  int v = (i < n) ? deg[i] : 0;
  for (int off = 32; off; off >>= 1) v += __shfl_down(v, off);
  __shared__ int wsum[4];
  int lane = threadIdx.x & 63, wid = threadIdx.x >> 6;
  if (lane == 0) wsum[wid] = v;
  __syncthreads();
  if (threadIdx.x == 0) bsum[blockIdx.x] = wsum[0] + wsum[1] + wsum[2] + wsum[3];
}

__global__ __launch_bounds__(512) void scanb_kernel(int* __restrict__ bsum, int nb) {
  __shared__ int s[512];
  int t = threadIdx.x;
  int orig = (t < nb) ? bsum[t] : 0;
  s[t] = orig;
  __syncthreads();
  for (int off = 1; off < 512; off <<= 1) {
    int add = (t >= off) ? s[t - off] : 0;
    __syncthreads();
    s[t] += add;
    __syncthreads();
  }
  if (t < nb) bsum[t] = s[t] - orig;   // exclusive
}

__global__ __launch_bounds__(BLK) void rowstart_kernel(const int* __restrict__ deg,
    const int* __restrict__ bsum, int* __restrict__ rowstart,
    int* __restrict__ cursor, int n) {
  __shared__ int s[BLK];
  int t = threadIdx.x, i = blockIdx.x * BLK + t;
  int orig = (i < n) ? deg[i] : 0;
  s[t] = orig;
  __syncthreads();
  for (int off = 1; off < BLK; off <<= 1) {
    int add = (t >= off) ? s[t - off] : 0;
    __syncthreads();
    s[t] += add;
    __syncthreads();
  }
  if (i < n) { int st = bsum[blockIdx.x] + s[t] - orig; rowstart[i] = st; cursor[i] = st; }
}

__global__ __launch_bounds__(BLK) void scatter_kernel(const int* __restrict__ src,
    const int* __restrict__ dst, int* __restrict__ cursor, int* __restrict__ eidx, int E) {
  int e = blockIdx.x * BLK + threadIdx.x;
  if (e >= E) return;
  int p = atomicAdd(&cursor[dst[e]], 1);
  eidx[p] = src[e];
}

// ---- fused gather-aggregate + residual: out = num/(den+1e-16) + x[d] ----
template<int C>
__global__ __launch_bounds__(BLK) void agg_kernel(const int* __restrict__ rowstart,
    const int* __restrict__ deg, const int* __restrict__ eidx,
    const float* __restrict__ x, float* __restrict__ out, int n) {
  int gid = blockIdx.x * BLK + threadIdx.x;
  int node = gid / C;
  int c = gid & (C - 1);
  if (node >= n) return;
  int s0 = rowstart[node];
  int d = deg[node];
  float den = 0.f, num = 0.f;
  int j = 0;
  for (; j + 1 < d; j += 2) {
    int sA = eidx[s0 + j], sB = eidx[s0 + j + 1];
    float xa = x[(size_t)sA * C + c];
    float xb = x[(size_t)sB * C + c];
    float ma = fmaxf(xa, 0.f) + F_EPS;
    float mb = fmaxf(xb, 0.f) + F_EPS;
    float aa = expf(ma), ab = expf(mb);
    den += aa + ab;
    num += ma * aa + mb * ab;
  }
  if (j < d) {
    int sA = eidx[s0 + j];
    float xa = x[(size_t)sA * C + c];
    float ma = fmaxf(xa, 0.f) + F_EPS;
    float aa = expf(ma);
    den += aa;
    num += ma * aa;
  }
  float xd = x[(size_t)node * C + c];
  out[(size_t)node * C + c] = num / (den + 1e-16f) + xd;
}

// ---- column sums for BN stats (FP64 accumulation to avoid cancellation) ----
template<int COUT>
__global__ __launch_bounds__(BLK) void stat_kernel(const float* __restrict__ h,
    double* __restrict__ gsum, double* __restrict__ gsq, int n) {
  constexpr int G = COUT / 4;
  constexpr int REPS = BLK / G;
  double s0 = 0, s1 = 0, s2 = 0, s3 = 0, q0 = 0, q1 = 0, q2 = 0, q3 = 0;
  int total4 = n * G;
  for (int i = blockIdx.x * BLK + threadIdx.x; i < total4; i += gridDim.x * BLK) {
    float4 v = reinterpret_cast<const float4*>(h)[i];
    double dx = v.x, dy = v.y, dz = v.z, dw = v.w;
    s0 += dx; q0 += dx * dx;
    s1 += dy; q1 += dy * dy;
    s2 += dz; q2 += dz * dz;
    s3 += dw; q3 += dw * dw;
  }
  __shared__ double sL[BLK * 8];
  double* my = sL + threadIdx.x * 8;
  my[0] = s0; my[1] = s1; my[2] = s2; my[3] = s3;
  my[4] = q0; my[5] = q1; my[6] = q2; my[7] = q3;
  __syncthreads();
  int g = threadIdx.x;
  if (g < G) {
    for (int r = 1; r < REPS; ++r) {
      double* o = sL + (g + r * G) * 8;
      s0 += o[0]; s1 += o[1]; s2 += o[2]; s3 += o[3];
      q0 += o[4]; q1 += o[5]; q2 += o[6]; q3 += o[7];
    }
    atomicAdd(&gsum[4*g+0], s0); atomicAdd(&gsum[4*g+1], s1);
    atomicAdd(&gsum[4*g+2], s2); atomicAdd(&gsum[4*g+3], s3);
    atomicAdd(&gsq[4*g+0], q0); atomicAdd(&gsq[4*g+1], q1);
    atomicAdd(&gsq[4*g+2], q2); atomicAdd(&gsq[4*g+3], q3);
  }
}

__global__ void bn_fin(const double* __restrict__ sum, const double* __restrict__ sq,
                       const float* __restrict__ g, const float* __restrict__ be,
                       float* __restrict__ sc, float* __restrict__ sh, int H, int n) {
  int j = threadIdx.x;
  if (j >= H) return;
  double inv_n = 1.0 / (double)n;
  double mu = sum[j] * inv_n;
  double var = sq[j] * inv_n - mu * mu;
  double s = (double)g[j] / sqrt(var + 1e-5);
  sc[j] = (float)s;
  sh[j] = (float)((double)be[j] - mu * s);
}

// ---- score + key + round-0 histogram (byte 7) ----
__global__ __launch_bounds__(BLK) void score_kernel(const float* __restrict__ x,
    const float* __restrict__ w, float* __restrict__ scores,
    u64* __restrict__ keys, int* __restrict__ ghist, int n) {
  __shared__ float sw[64];
  __shared__ float snorm;
  __shared__ int hl[256];
  if (threadIdx.x < 64) sw[threadIdx.x] = w[threadIdx.x];
  hl[threadIdx.x] = 0;
  __syncthreads();
  if (threadIdx.x < 64) {
    float v = sw[threadIdx.x];
    float sq = v * v;
    for (int off = 32; off; off >>= 1) sq += __shfl_down(sq, off);
    if (threadIdx.x == 0) snorm = 1.f / sqrtf(sq);
  }
  __syncthreads();
  int node = blockIdx.x * BLK + threadIdx.x;
  if (node < n) {
    const float4* row = reinterpret_cast<const float4*>(x + (size_t)node * 64);
    float acc = 0.f;
    #pragma unroll
    for (int k4 = 0; k4 < 16; ++k4) {
      float4 v = row[k4];
      const float4 wv = *reinterpret_cast<const float4*>(&sw[4 * k4]);
      acc += v.x * wv.x + v.y * wv.y + v.z * wv.z + v.w * wv.w;
    }
    float s = tanhf(acc * snorm);
    scores[node] = s;
    u64 key = ((u64)ord_f32(s) << 32) | (unsigned int)(~node);
    keys[node] = key;
    atomicAdd(&hl[(int)(key >> 56)], 1);
  }
  __syncthreads();
  int v = hl[threadIdx.x];
  if (v) atomicAdd(&ghist[threadIdx.x], v);
}

// istate: [0]=k remaining [1]=digit [2]=sel count [4]=out count
__global__ void pick0_kernel(int* __restrict__ istate, const int* __restrict__ hist) {
  if (threadIdx.x == 0) {
    int k = TOPK, run = 0;
    for (int d = 255; d >= 0; --d) {
      int c = hist[d];
      if (run + c >= k) { istate[1] = d; istate[0] = k - run; break; }
      run += c;
    }
    istate[2] = 0; istate[4] = 0;
  }
}

__global__ __launch_bounds__(BLK) void compact0_kernel(const u64* __restrict__ in,
    u64* __restrict__ outb, u64* __restrict__ sel, int* __restrict__ istate, int n) {
  int i = blockIdx.x * BLK + threadIdx.x;
  if (i >= n) return;
  u64 kkey = in[i];
  int b = (int)(kkey >> 56);
  int digit = istate[1];
  if (b > digit) {
    sel[atomicAdd(&istate[2], 1)] = kkey;
  } else if (b == digit) {
    outb[atomicAdd(&istate[4], 1)] = kkey;
  }
}

// ---- single block: radix rounds 1..7 + append + bitonic sort + gather ----
__global__ __launch_bounds__(1024) void topk_finish(u64* __restrict__ bufB,
    u64* __restrict__ bufA, u64* __restrict__ sel, const int* __restrict__ istate,
    const float* __restrict__ scores, const float* __restrict__ x,
    float* __restrict__ out) {
  __shared__ int hl[256];
  __shared__ int sh_digit, sh_k, sh_sel, sh_out, sh_cnt;
  __shared__ u64 sk[512];
  int t = threadIdx.x;
  if (t == 0) { sh_cnt = istate[4]; sh_k = istate[0]; sh_sel = istate[2]; }
  __syncthreads();
  u64* cur = bufB;
  u64* nxt = bufA;
  for (int shift = 48; shift >= 0; shift -= 8) {
    for (int i = t; i < 256; i += 1024) hl[i] = 0;
    __syncthreads();
    int cnt = sh_cnt;
    for (int i = t; i < cnt; i += 1024) atomicAdd(&hl[(int)((cur[i] >> shift) & 255ull)], 1);
    __syncthreads();
    if (t == 0) {
      int k = sh_k, run = 0;
      for (int d = 255; d >= 0; --d) {
        int c = hl[d];
        if (run + c >= k) { sh_digit = d; sh_k = k - run; break; }
        run += c;
      }
      sh_out = 0;
    }
    __syncthreads();
    int digit = sh_digit;
    for (int i = t; i < cnt; i += 1024) {
      u64 kk = cur[i];
      int b = (int)((kk >> shift) & 255ull);
      if (b > digit) sel[atomicAdd(&sh_sel, 1)] = kk;
      else if (b == digit) nxt[atomicAdd(&sh_out, 1)] = kk;
    }
    __syncthreads();
    if (t == 0) sh_cnt = sh_out;
    __syncthreads();
    u64* tmp = cur; cur = nxt; nxt = tmp;
  }
  int base = sh_sel, krem = sh_k;
  for (int i = t; i < krem; i += 1024) sel[base + i] = cur[i];
  __syncthreads();
  if (t < 512) sk[t] = sel[t];
  __syncthreads();
  for (int k = 2; k <= 512; k <<= 1) {
    for (int j = k >> 1; j > 0; j >>= 1) {
      if (t < 512) {
        int ixj = t ^ j;
        if (ixj > t) {
          bool dirDesc = ((t & k) == 0);
          u64 A = sk[t], B = sk[ixj];
          bool swp = dirDesc ? (A < B) : (A > B);
          if (swp) { sk[t] = B; sk[ixj] = A; }
        }
      }
      __syncthreads();
    }
  }
  for (int i = t; i < 512 * 16; i += 1024) {
    int r = i >> 4, c = i & 15;
    u64 kk = sk[r];
    int nidx = (int)(~(unsigned int)(kk & 0xffffffffull));
    float v = scores[nidx];
    float4 xv = reinterpret_cast<const float4*>(x)[(size_t)nidx * 16 + c];
    float4 r4; r4.x = xv.x * v; r4.y = xv.y * v; r4.z = xv.z * v; r4.w = xv.w * v;
    reinterpret_cast<float4*>(out)[(size_t)r * 16 + c] = r4;
  }
}

extern "C" void kernel_launch(void* const* d_in, const int* in_sizes, int n_in,
                              void* d_out, int out_size, void* d_ws, size_t ws_size,
                              hipStream_t stream) {
  const int N = in_sizes[0] / 3;
  const int E = in_sizes[1] / 2;

  const float* pos   = (const float*)d_in[0];
  const int*   ei    = (const int*)d_in[1];
  const int*   src   = ei;
  const int*   dst   = ei + E;
  const float* c1_lw = (const float*)d_in[2];
  const float* c1_lb = (const float*)d_in[3];
  const float* c1_w1 = (const float*)d_in[4];
  const float* c1_b1 = (const float*)d_in[5];
  const float* c1_g1 = (const float*)d_in[6];
  const float* c1_be1= (const float*)d_in[7];
  const float* c1_w2 = (const float*)d_in[8];
  const float* c1_b2 = (const float*)d_in[9];
  const float* c2_lw = (const float*)d_in[10];
  const float* c2_lb = (const float*)d_in[11];
  const float* c2_w1 = (const float*)d_in[12];
  const float* c2_b1 = (const float*)d_in[13];
  const float* c2_g1 = (const float*)d_in[14];
  const float* c2_be1= (const float*)d_in[15];
  const float* c2_w2 = (const float*)d_in[16];
  const float* c2_b2 = (const float*)d_in[17];
  const float* poolw = (const float*)d_in[18];

  // ---- workspace layout ----
  float* ws = (float*)d_ws;
  float* x1   = ws;                         // 16N (base block: 64N; res2 reuses it)
  float* h1   = ws + (size_t)16 * N;        // 32N
  float* o1   = ws + (size_t)48 * N;        // 16N
  float* res2 = ws;                         // 64N (after x1/h1/o1 are dead)
  float* x2   = ws + (size_t)64 * N;        // 64N  (res1 uses this region first)
  float* res1 = x2;                         // 16N (dead before lin<16,64> writes x2)
  float* h2   = ws + (size_t)128 * N;       // 128N
  float* o2   = ws + (size_t)256 * N;       // 64N
  float* scores = ws + (size_t)320 * N;     // N
  u64* candA = (u64*)(ws + (size_t)321 * N);            // N
  u64* candB = candA + N;                               // N
  u64* sel   = candB + N;                               // 512
  double* dstat = (double*)(sel + TOPK);                // 320 doubles
  double* sum1 = dstat;        double* sq1 = dstat + 32;
  double* sum2 = dstat + 64;   double* sq2 = dstat + 192;
  int* ibase   = (int*)(dstat + 320);
  int* istate  = ibase;            // 8
  int* hist    = ibase + 8;        // 256
  int* bsum    = ibase + 264;      // 512
  int* deg     = ibase + 776;      // N
  int* rowstart= deg + N;          // N
  int* cursor  = rowstart + N;     // N
  int* eidx    = cursor + N;       // E
  float* fsc   = (float*)(eidx + E);
  float* sc1 = fsc;        float* sh1 = fsc + 32;
  float* sc2 = fsc + 64;   float* sh2 = fsc + 192;     // 320 floats total

  const int nbN = (N + BLK - 1) / BLK;
  const int nbE = (E + BLK - 1) / BLK;

  // replay-safe zeroing
  hipMemsetAsync(deg, 0, (size_t)N * sizeof(int), stream);
  hipMemsetAsync(dstat, 0, 320 * sizeof(double) + 776 * sizeof(int), stream);

  // ---- CSR build (shared by both convs) ----
  deg_kernel<<<nbE, BLK, 0, stream>>>(dst, deg, E);
  blocksum_kernel<<<nbN, BLK, 0, stream>>>(deg, bsum, N);
  scanb_kernel<<<1, 512, 0, stream>>>(bsum, nbN);
  rowstart_kernel<<<nbN, BLK, 0, stream>>>(deg, bsum, rowstart, cursor, N);
  scatter_kernel<<<nbE, BLK, 0, stream>>>(src, dst, cursor, eidx, E);

  // ---- conv1 ----
  lin_kernel<3, 16><<<nbN, BLK, 0, stream>>>(pos, c1_lw, c1_lb, x1, N);
  agg_kernel<16><<<(N * 16 + BLK - 1) / BLK, BLK, 0, stream>>>(rowstart, deg, eidx, x1, res1, N);
  lin_kernel<16, 32><<<nbN, BLK, 0, stream>>>(res1, c1_w1, c1_b1, h1, N);
  stat_kernel<32><<<2048, BLK, 0, stream>>>(h1, sum1, sq1, N);
  bn_fin<<<1, 32, 0, stream>>>(sum1, sq1, c1_g1, c1_be1, sc1, sh1, 32, N);
  mlp2_kernel<32, 16><<<nbN, BLK, 0, stream>>>(h1, sc1, sh1, c1_w2, c1_b2, o1, N);

  // ---- conv2 ----
  lin_kernel<16, 64><<<nbN, BLK, 0, stream>>>(o1, c2_lw, c2_lb, x2, N);
  agg_kernel<64><<<(N * 64 + BLK - 1) / BLK, BLK, 0, stream>>>(rowstart, deg, eidx, x2, res2, N);
  lin_kernel<64, 128><<<nbN, BLK, 0, stream>>>(res2, c2_w1, c2_b1, h2, N);
  stat_kernel<128><<<2048, BLK, 0, stream>>>(h2, sum2, sq2, N);
  bn_fin<<<1, 128, 0, stream>>>(sum2, sq2, c2_g1, c2_be1, sc2, sh2, 128, N);
  mlp2_kernel<128, 64><<<nbN, BLK, 0, stream>>>(h2, sc2, sh2, c2_w2, c2_b2, o2, N);

  // ---- scores + exact top-K ----
  score_kernel<<<nbN, BLK, 0, stream>>>(o2, poolw, scores, candA, hist, N);
  pick0_kernel<<<1, 64, 0, stream>>>(istate, hist);
  compact0_kernel<<<nbN, BLK, 0, stream>>>(candA, candB, sel, istate, N);
  topk_finish<<<1, 1024, 0, stream>>>(candB, candA, sel, istate, scores, o2, (float*)d_out);

  (void)n_in; (void)out_size; (void)ws_size;
}

// Round 4
// 636.893 us; speedup vs baseline: 5.4000x; 1.5369x over previous
//
#include <hip/hip_runtime.h>
#include <stdint.h>

#define BLK 256

static constexpr float F_EPS = 1e-7f;   // GENConv message eps
static constexpr float F_NEG = 0.01f;   // LeakyReLU slope
static constexpr int   TOPK  = 512;
static constexpr int   STATNB = 1024;   // stat_kernel grid (fixed, partial slots)

typedef unsigned long long u64;

__device__ __forceinline__ unsigned int ord_f32(float f) {
  unsigned int u = __float_as_uint(f);
  return (u & 0x80000000u) ? ~u : (u | 0x80000000u);
}

// ---------------- dense: out[n,COUT] = in[n,CIN] @ W + b ----------------
template<int CIN, int COUT>
__global__ __launch_bounds__(BLK) void lin_kernel(const float* __restrict__ in,
    const float* __restrict__ W, const float* __restrict__ b,
    float* __restrict__ out, int n) {
  __shared__ __align__(16) float sW[CIN * COUT];
  __shared__ float sB[COUT];
  for (int i = threadIdx.x; i < CIN * COUT; i += BLK) sW[i] = W[i];
  for (int i = threadIdx.x; i < COUT; i += BLK) sB[i] = b[i];
  __syncthreads();
  int node = blockIdx.x * BLK + threadIdx.x;
  if (node >= n) return;
  float x[CIN];
  if constexpr ((CIN & 3) == 0) {
    const float4* row = reinterpret_cast<const float4*>(in + (size_t)node * CIN);
    #pragma unroll
    for (int k4 = 0; k4 < CIN / 4; ++k4) {
      float4 v = row[k4];
      x[4*k4+0] = v.x; x[4*k4+1] = v.y; x[4*k4+2] = v.z; x[4*k4+3] = v.w;
    }
  } else {
    #pragma unroll
    for (int k = 0; k < CIN; ++k) x[k] = in[(size_t)node * CIN + k];
  }
  float* orow = out + (size_t)node * COUT;
  for (int j = 0; j < COUT; j += 4) {
    float a0 = sB[j], a1 = sB[j+1], a2 = sB[j+2], a3 = sB[j+3];
    #pragma unroll
    for (int k = 0; k < CIN; ++k) {
      const float4 w = *reinterpret_cast<const float4*>(&sW[k * COUT + j]);
      a0 += x[k] * w.x; a1 += x[k] * w.y; a2 += x[k] * w.z; a3 += x[k] * w.w;
    }
    float4 r; r.x = a0; r.y = a1; r.z = a2; r.w = a3;
    *reinterpret_cast<float4*>(orow + j) = r;
  }
}

// ---- MLP second half: t=relu(h*scale+shift); out=leaky(t@W+b) ----
template<int CIN, int COUT>
__global__ __launch_bounds__(BLK) void mlp2_kernel(const float* __restrict__ h,
    const float* __restrict__ scale, const float* __restrict__ shift,
    const float* __restrict__ W, const float* __restrict__ b,
    float* __restrict__ out, int n) {
  __shared__ __align__(16) float sW[CIN * COUT];
  __shared__ float sB[COUT];
  __shared__ float sSc[CIN];
  __shared__ float sSh[CIN];
  for (int i = threadIdx.x; i < CIN * COUT; i += BLK) sW[i] = W[i];
  for (int i = threadIdx.x; i < COUT; i += BLK) sB[i] = b[i];
  for (int i = threadIdx.x; i < CIN; i += BLK) { sSc[i] = scale[i]; sSh[i] = shift[i]; }
  __syncthreads();
  int node = blockIdx.x * BLK + threadIdx.x;
  if (node >= n) return;
  float t[CIN];
  const float4* row = reinterpret_cast<const float4*>(h + (size_t)node * CIN);
  #pragma unroll
  for (int k4 = 0; k4 < CIN / 4; ++k4) {
    float4 v = row[k4];
    t[4*k4+0] = fmaxf(v.x * sSc[4*k4+0] + sSh[4*k4+0], 0.f);
    t[4*k4+1] = fmaxf(v.y * sSc[4*k4+1] + sSh[4*k4+1], 0.f);
    t[4*k4+2] = fmaxf(v.z * sSc[4*k4+2] + sSh[4*k4+2], 0.f);
    t[4*k4+3] = fmaxf(v.w * sSc[4*k4+3] + sSh[4*k4+3], 0.f);
  }
  float* orow = out + (size_t)node * COUT;
  for (int j = 0; j < COUT; j += 4) {
    float a0 = sB[j], a1 = sB[j+1], a2 = sB[j+2], a3 = sB[j+3];
    #pragma unroll
    for (int k = 0; k < CIN; ++k) {
      const float4 w = *reinterpret_cast<const float4*>(&sW[k * COUT + j]);
      a0 += t[k] * w.x; a1 += t[k] * w.y; a2 += t[k] * w.z; a3 += t[k] * w.w;
    }
    a0 = a0 > 0.f ? a0 : F_NEG * a0;
    a1 = a1 > 0.f ? a1 : F_NEG * a1;
    a2 = a2 > 0.f ? a2 : F_NEG * a2;
    a3 = a3 > 0.f ? a3 : F_NEG * a3;
    float4 r; r.x = a0; r.y = a1; r.z = a2; r.w = a3;
    *reinterpret_cast<float4*>(orow + j) = r;
  }
}

// ---------------- CSR build ----------------
__global__ __launch_bounds__(BLK) void deg_kernel(const int* __restrict__ dst,
    int* __restrict__ deg, int E) {
  int e = blockIdx.x * BLK + threadIdx.x;
  if (e < E) atomicAdd(&deg[dst[e]], 1);
}

__global__ __launch_bounds__(BLK) void blocksum_kernel(const int* __restrict__ deg,
    int* __restrict__ bsum, int n) {
  int i = blockIdx.x * BLK + threadIdx.x;
  int v = (i < n) ? deg[i] : 0;
  for (int off = 32; off; off >>= 1) v += __shfl_down(v, off);
  __shared__ int wsum[4];
  int lane = threadIdx.x & 63, wid = threadIdx.x >> 6;
  if (lane == 0) wsum[wid] = v;
  __syncthreads();
  if (threadIdx.x == 0) bsum[blockIdx.x] = wsum[0] + wsum[1] + wsum[2] + wsum[3];
}

__global__ __launch_bounds__(512) void scanb_kernel(int* __restrict__ bsum, int nb) {
  __shared__ int s[512];
  int t = threadIdx.x;
  int orig = (t < nb) ? bsum[t] : 0;
  s[t] = orig;
  __syncthreads();
  for (int off = 1; off < 512; off <<= 1) {
    int add = (t >= off) ? s[t - off] : 0;
    __syncthreads();
    s[t] += add;
    __syncthreads();
  }
  if (t < nb) bsum[t] = s[t] - orig;   // exclusive
}

__global__ __launch_bounds__(BLK) void rowstart_kernel(const int* __restrict__ deg,
    const int* __restrict__ bsum, int* __restrict__ rowstart,
    int* __restrict__ cursor, int n) {
  __shared__ int s[BLK];
  int t = threadIdx.x, i = blockIdx.x * BLK + t;
  int orig = (i < n) ? deg[i] : 0;
  s[t] = orig;
  __syncthreads();
  for (int off = 1; off < BLK; off <<= 1) {
    int add = (t >= off) ? s[t - off] : 0;
    __syncthreads();
    s[t] += add;
    __syncthreads();
  }
  if (i < n) { int st = bsum[blockIdx.x] + s[t] - orig; rowstart[i] = st; cursor[i] = st; }
}

__global__ __launch_bounds__(BLK) void scatter_kernel(const int* __restrict__ src,
    const int* __restrict__ dst, int* __restrict__ cursor, int* __restrict__ eidx, int E) {
  int e = blockIdx.x * BLK + threadIdx.x;
  if (e >= E) return;
  int p = atomicAdd(&cursor[dst[e]], 1);
  eidx[p] = src[e];
}

// ---- fused gather-aggregate + residual: out = num/(den+1e-16) + x[d] ----
template<int C>
__global__ __launch_bounds__(BLK) void agg_kernel(const int* __restrict__ rowstart,
    const int* __restrict__ deg, const int* __restrict__ eidx,
    const float* __restrict__ x, float* __restrict__ out, int n) {
  int gid = blockIdx.x * BLK + threadIdx.x;
  int node = gid / C;
  int c = gid & (C - 1);
  if (node >= n) return;
  int s0 = rowstart[node];
  int d = deg[node];
  float den = 0.f, num = 0.f;
  int j = 0;
  for (; j + 1 < d; j += 2) {
    int sA = eidx[s0 + j], sB = eidx[s0 + j + 1];
    float xa = x[(size_t)sA * C + c];
    float xb = x[(size_t)sB * C + c];
    float ma = fmaxf(xa, 0.f) + F_EPS;
    float mb = fmaxf(xb, 0.f) + F_EPS;
    float aa = expf(ma), ab = expf(mb);
    den += aa + ab;
    num += ma * aa + mb * ab;
  }
  if (j < d) {
    int sA = eidx[s0 + j];
    float xa = x[(size_t)sA * C + c];
    float ma = fmaxf(xa, 0.f) + F_EPS;
    float aa = expf(ma);
    den += aa;
    num += ma * aa;
  }
  float xd = x[(size_t)node * C + c];
  out[(size_t)node * C + c] = num / (den + 1e-16f) + xd;
}

// ---- BN stats pass 1: per-block f64 partial column sums (NO atomics) ----
// partial layout: [STATNB][2*COUT] : sums then sumsqs
template<int COUT>
__global__ __launch_bounds__(BLK) void stat_kernel(const float* __restrict__ h,
    double* __restrict__ partial, int n) {
  constexpr int G = COUT / 4;
  constexpr int REPS = BLK / G;
  double s0 = 0, s1 = 0, s2 = 0, s3 = 0, q0 = 0, q1 = 0, q2 = 0, q3 = 0;
  int total4 = n * G;
  for (int i = blockIdx.x * BLK + threadIdx.x; i < total4; i += gridDim.x * BLK) {
    float4 v = reinterpret_cast<const float4*>(h)[i];
    double dx = v.x, dy = v.y, dz = v.z, dw = v.w;
    s0 += dx; q0 += dx * dx;
    s1 += dy; q1 += dy * dy;
    s2 += dz; q2 += dz * dz;
    s3 += dw; q3 += dw * dw;
  }
  __shared__ double sL[BLK * 8];
  double* my = sL + threadIdx.x * 8;
  my[0] = s0; my[1] = s1; my[2] = s2; my[3] = s3;
  my[4] = q0; my[5] = q1; my[6] = q2; my[7] = q3;
  __syncthreads();
  int g = threadIdx.x;
  if (g < G) {
    for (int r = 1; r < REPS; ++r) {
      double* o = sL + (g + r * G) * 8;
      s0 += o[0]; s1 += o[1]; s2 += o[2]; s3 += o[3];
      q0 += o[4]; q1 += o[5]; q2 += o[6]; q3 += o[7];
    }
    double* prow = partial + (size_t)blockIdx.x * (2 * COUT);
    prow[4*g+0] = s0; prow[4*g+1] = s1; prow[4*g+2] = s2; prow[4*g+3] = s3;
    prow[COUT+4*g+0] = q0; prow[COUT+4*g+1] = q1;
    prow[COUT+4*g+2] = q2; prow[COUT+4*g+3] = q3;
  }
}

// ---- BN stats pass 2: one block per channel reduces STATNB partials ----
template<int COUT>
__global__ __launch_bounds__(256) void bn_fin2(const double* __restrict__ partial,
    const float* __restrict__ g, const float* __restrict__ be,
    float* __restrict__ sc, float* __restrict__ sh, int n) {
  int j = blockIdx.x;
  int t = threadIdx.x;
  double s = 0, q = 0;
  for (int b = t; b < STATNB; b += 256) {
    const double* prow = partial + (size_t)b * (2 * COUT);
    s += prow[j];
    q += prow[COUT + j];
  }
  for (int off = 32; off; off >>= 1) { s += __shfl_down(s, off); q += __shfl_down(q, off); }
  __shared__ double sw[4][2];
  int lane = t & 63, wid = t >> 6;
  if (lane == 0) { sw[wid][0] = s; sw[wid][1] = q; }
  __syncthreads();
  if (t == 0) {
    s = sw[0][0] + sw[1][0] + sw[2][0] + sw[3][0];
    q = sw[0][1] + sw[1][1] + sw[2][1] + sw[3][1];
    double inv_n = 1.0 / (double)n;
    double mu = s * inv_n;
    double var = q * inv_n - mu * mu;
    double scd = (double)g[j] / sqrt(var + 1e-5);
    sc[j] = (float)scd;
    sh[j] = (float)((double)be[j] - mu * scd);
  }
}

// ---- score + key + round-0 histogram (byte 7) ----
__global__ __launch_bounds__(BLK) void score_kernel(const float* __restrict__ x,
    const float* __restrict__ w, float* __restrict__ scores,
    u64* __restrict__ keys, int* __restrict__ ghist, int n) {
  __shared__ float sw[64];
  __shared__ float snorm;
  __shared__ int hl[256];
  if (threadIdx.x < 64) sw[threadIdx.x] = w[threadIdx.x];
  hl[threadIdx.x] = 0;
  __syncthreads();
  if (threadIdx.x < 64) {
    float v = sw[threadIdx.x];
    float sq = v * v;
    for (int off = 32; off; off >>= 1) sq += __shfl_down(sq, off);
    if (threadIdx.x == 0) snorm = 1.f / sqrtf(sq);
  }
  __syncthreads();
  int node = blockIdx.x * BLK + threadIdx.x;
  if (node < n) {
    const float4* row = reinterpret_cast<const float4*>(x + (size_t)node * 64);
    float acc = 0.f;
    #pragma unroll
    for (int k4 = 0; k4 < 16; ++k4) {
      float4 v = row[k4];
      const float4 wv = *reinterpret_cast<const float4*>(&sw[4 * k4]);
      acc += v.x * wv.x + v.y * wv.y + v.z * wv.z + v.w * wv.w;
    }
    float s = tanhf(acc * snorm);
    scores[node] = s;
    u64 key = ((u64)ord_f32(s) << 32) | (unsigned int)(~node);
    keys[node] = key;
    atomicAdd(&hl[(int)(key >> 56)], 1);
  }
  __syncthreads();
  int v = hl[threadIdx.x];
  if (v) atomicAdd(&ghist[threadIdx.x], v);
}

// istate: [0]=k remaining [1]=digit [2]=sel count [4]=out count
__global__ void pick0_kernel(int* __restrict__ istate, const int* __restrict__ hist) {
  if (threadIdx.x == 0) {
    int k = TOPK, run = 0;
    for (int d = 255; d >= 0; --d) {
      int c = hist[d];
      if (run + c >= k) { istate[1] = d; istate[0] = k - run; break; }
      run += c;
    }
    istate[2] = 0; istate[4] = 0;
  }
}

__global__ __launch_bounds__(BLK) void compact0_kernel(const u64* __restrict__ in,
    u64* __restrict__ outb, u64* __restrict__ sel, int* __restrict__ istate, int n) {
  int i = blockIdx.x * BLK + threadIdx.x;
  if (i >= n) return;
  u64 kkey = in[i];
  int b = (int)(kkey >> 56);
  int digit = istate[1];
  if (b > digit) {
    sel[atomicAdd(&istate[2], 1)] = kkey;
  } else if (b == digit) {
    outb[atomicAdd(&istate[4], 1)] = kkey;
  }
}

// ---- single block: radix rounds 1..7 + append + bitonic sort + gather ----
__global__ __launch_bounds__(1024) void topk_finish(u64* __restrict__ bufB,
    u64* __restrict__ bufA, u64* __restrict__ sel, const int* __restrict__ istate,
    const float* __restrict__ scores, const float* __restrict__ x,
    float* __restrict__ out) {
  __shared__ int hl[256];
  __shared__ int sh_digit, sh_k, sh_sel, sh_out, sh_cnt;
  __shared__ u64 sk[512];
  int t = threadIdx.x;
  if (t == 0) { sh_cnt = istate[4]; sh_k = istate[0]; sh_sel = istate[2]; }
  __syncthreads();
  u64* cur = bufB;
  u64* nxt = bufA;
  for (int shift = 48; shift >= 0; shift -= 8) {
    for (int i = t; i < 256; i += 1024) hl[i] = 0;
    __syncthreads();
    int cnt = sh_cnt;
    for (int i = t; i < cnt; i += 1024) atomicAdd(&hl[(int)((cur[i] >> shift) & 255ull)], 1);
    __syncthreads();
    if (t == 0) {
      int k = sh_k, run = 0;
      for (int d = 255; d >= 0; --d) {
        int c = hl[d];
        if (run + c >= k) { sh_digit = d; sh_k = k - run; break; }
        run += c;
      }
      sh_out = 0;
    }
    __syncthreads();
    int digit = sh_digit;
    for (int i = t; i < cnt; i += 1024) {
      u64 kk = cur[i];
      int b = (int)((kk >> shift) & 255ull);
      if (b > digit) sel[atomicAdd(&sh_sel, 1)] = kk;
      else if (b == digit) nxt[atomicAdd(&sh_out, 1)] = kk;
    }
    __syncthreads();
    if (t == 0) sh_cnt = sh_out;
    __syncthreads();
    u64* tmp = cur; cur = nxt; nxt = tmp;
  }
  int base = sh_sel, krem = sh_k;
  for (int i = t; i < krem; i += 1024) sel[base + i] = cur[i];
  __syncthreads();
  if (t < 512) sk[t] = sel[t];
  __syncthreads();
  for (int k = 2; k <= 512; k <<= 1) {
    for (int j = k >> 1; j > 0; j >>= 1) {
      if (t < 512) {
        int ixj = t ^ j;
        if (ixj > t) {
          bool dirDesc = ((t & k) == 0);
          u64 A = sk[t], B = sk[ixj];
          bool swp = dirDesc ? (A < B) : (A > B);
          if (swp) { sk[t] = B; sk[ixj] = A; }
        }
      }
      __syncthreads();
    }
  }
  for (int i = t; i < 512 * 16; i += 1024) {
    int r = i >> 4, c = i & 15;
    u64 kk = sk[r];
    int nidx = (int)(~(unsigned int)(kk & 0xffffffffull));
    float v = scores[nidx];
    float4 xv = reinterpret_cast<const float4*>(x)[(size_t)nidx * 16 + c];
    float4 r4; r4.x = xv.x * v; r4.y = xv.y * v; r4.z = xv.z * v; r4.w = xv.w * v;
    reinterpret_cast<float4*>(out)[(size_t)r * 16 + c] = r4;
  }
}

extern "C" void kernel_launch(void* const* d_in, const int* in_sizes, int n_in,
                              void* d_out, int out_size, void* d_ws, size_t ws_size,
                              hipStream_t stream) {
  const int N = in_sizes[0] / 3;
  const int E = in_sizes[1] / 2;

  const float* pos   = (const float*)d_in[0];
  const int*   ei    = (const int*)d_in[1];
  const int*   src   = ei;
  const int*   dst   = ei + E;
  const float* c1_lw = (const float*)d_in[2];
  const float* c1_lb = (const float*)d_in[3];
  const float* c1_w1 = (const float*)d_in[4];
  const float* c1_b1 = (const float*)d_in[5];
  const float* c1_g1 = (const float*)d_in[6];
  const float* c1_be1= (const float*)d_in[7];
  const float* c1_w2 = (const float*)d_in[8];
  const float* c1_b2 = (const float*)d_in[9];
  const float* c2_lw = (const float*)d_in[10];
  const float* c2_lb = (const float*)d_in[11];
  const float* c2_w1 = (const float*)d_in[12];
  const float* c2_b1 = (const float*)d_in[13];
  const float* c2_g1 = (const float*)d_in[14];
  const float* c2_be1= (const float*)d_in[15];
  const float* c2_w2 = (const float*)d_in[16];
  const float* c2_b2 = (const float*)d_in[17];
  const float* poolw = (const float*)d_in[18];

  // ---- workspace layout ----
  float* ws = (float*)d_ws;
  float* x1   = ws;                         // 16N
  float* h1   = ws + (size_t)16 * N;        // 32N
  float* o1   = ws + (size_t)48 * N;        // 16N
  float* res2 = ws;                         // 64N (after x1/h1/o1 dead)
  float* x2   = ws + (size_t)64 * N;        // 64N (res1 uses this region first)
  float* res1 = x2;                         // 16N (dead before lin<16,64> writes x2)
  float* h2   = ws + (size_t)128 * N;       // 128N
  float* o2   = ws + (size_t)256 * N;       // 64N
  float* scores = ws + (size_t)320 * N;     // N
  u64* candA = (u64*)(ws + (size_t)321 * N);            // N
  u64* candB = candA + N;                               // N
  u64* sel   = candB + N;                               // 512
  double* partial = (double*)(sel + TOPK);              // STATNB * 256 doubles (2 MB)
  int* ibase   = (int*)(partial + (size_t)STATNB * 256);
  int* istate  = ibase;            // 8
  int* hist    = ibase + 8;        // 256
  int* bsum    = ibase + 264;      // 512
  int* deg     = ibase + 776;      // N
  int* rowstart= deg + N;          // N
  int* cursor  = rowstart + N;     // N
  int* eidx    = cursor + N;       // E
  float* fsc   = (float*)(eidx + E);
  float* sc1 = fsc;        float* sh1 = fsc + 32;
  float* sc2 = fsc + 64;   float* sh2 = fsc + 192;     // 320 floats total

  const int nbN = (N + BLK - 1) / BLK;
  const int nbE = (E + BLK - 1) / BLK;

  // replay-safe zeroing: only deg + hist need it (atomic accumulation targets)
  hipMemsetAsync(deg, 0, (size_t)N * sizeof(int), stream);
  hipMemsetAsync(hist, 0, 256 * sizeof(int), stream);

  // ---- CSR build (shared by both convs) ----
  deg_kernel<<<nbE, BLK, 0, stream>>>(dst, deg, E);
  blocksum_kernel<<<nbN, BLK, 0, stream>>>(deg, bsum, N);
  scanb_kernel<<<1, 512, 0, stream>>>(bsum, nbN);
  rowstart_kernel<<<nbN, BLK, 0, stream>>>(deg, bsum, rowstart, cursor, N);
  scatter_kernel<<<nbE, BLK, 0, stream>>>(src, dst, cursor, eidx, E);

  // ---- conv1 ----
  lin_kernel<3, 16><<<nbN, BLK, 0, stream>>>(pos, c1_lw, c1_lb, x1, N);
  agg_kernel<16><<<(N * 16 + BLK - 1) / BLK, BLK, 0, stream>>>(rowstart, deg, eidx, x1, res1, N);
  lin_kernel<16, 32><<<nbN, BLK, 0, stream>>>(res1, c1_w1, c1_b1, h1, N);
  stat_kernel<32><<<STATNB, BLK, 0, stream>>>(h1, partial, N);
  bn_fin2<32><<<32, 256, 0, stream>>>(partial, c1_g1, c1_be1, sc1, sh1, N);
  mlp2_kernel<32, 16><<<nbN, BLK, 0, stream>>>(h1, sc1, sh1, c1_w2, c1_b2, o1, N);

  // ---- conv2 ----
  lin_kernel<16, 64><<<nbN, BLK, 0, stream>>>(o1, c2_lw, c2_lb, x2, N);
  agg_kernel<64><<<(N * 64 + BLK - 1) / BLK, BLK, 0, stream>>>(rowstart, deg, eidx, x2, res2, N);
  lin_kernel<64, 128><<<nbN, BLK, 0, stream>>>(res2, c2_w1, c2_b1, h2, N);
  stat_kernel<128><<<STATNB, BLK, 0, stream>>>(h2, partial, N);
  bn_fin2<128><<<128, 256, 0, stream>>>(partial, c2_g1, c2_be1, sc2, sh2, N);
  mlp2_kernel<128, 64><<<nbN, BLK, 0, stream>>>(h2, sc2, sh2, c2_w2, c2_b2, o2, N);

  // ---- scores + exact top-K ----
  score_kernel<<<nbN, BLK, 0, stream>>>(o2, poolw, scores, candA, hist, N);
  pick0_kernel<<<1, 64, 0, stream>>>(istate, hist);
  compact0_kernel<<<nbN, BLK, 0, stream>>>(candA, candB, sel, istate, N);
  topk_finish<<<1, 1024, 0, stream>>>(candB, candA, sel, istate, scores, o2, (float*)d_out);

  (void)n_in; (void)out_size; (void)ws_size;
}

// Round 5
// 554.933 us; speedup vs baseline: 6.1975x; 1.1477x over previous
//
#include <hip/hip_runtime.h>
#include <stdint.h>

#define BLK 256

static constexpr float F_EPS = 1e-7f;   // GENConv message eps
static constexpr float F_NEG = 0.01f;   // LeakyReLU slope
static constexpr int   TOPK  = 512;
static constexpr int   STATNB = 1024;   // stat_kernel grid (fixed, partial slots)

typedef unsigned long long u64;

__device__ __forceinline__ unsigned int ord_f32(float f) {
  unsigned int u = __float_as_uint(f);
  return (u & 0x80000000u) ? ~u : (u | 0x80000000u);
}

// ------- dense: out[n, j0:j0+JT] = in[n,:CIN] @ W[:, j0:j0+JT] + b -------
// grid = (ceil(n/BLK), COUT/JT). Per-thread: JT accumulators (ILP), k-chunked x.
template<int CIN, int COUT, int JT>
__global__ __launch_bounds__(BLK) void lin_kernel(const float* __restrict__ in,
    const float* __restrict__ W, const float* __restrict__ b,
    float* __restrict__ out, int n) {
  __shared__ float sW[CIN * JT];
  __shared__ float sB[JT];
  const int j0 = blockIdx.y * JT;
  for (int i = threadIdx.x; i < CIN * JT; i += BLK) {
    int k = i / JT, jj = i - k * JT;
    sW[i] = W[k * COUT + j0 + jj];
  }
  for (int i = threadIdx.x; i < JT; i += BLK) sB[i] = b[j0 + i];
  __syncthreads();
  int node = blockIdx.x * BLK + threadIdx.x;
  if (node >= n) return;
  float acc[JT];
  #pragma unroll
  for (int jj = 0; jj < JT; ++jj) acc[jj] = sB[jj];
  const float* xrow = in + (size_t)node * CIN;
  if constexpr ((CIN & 3) == 0) {
    constexpr int KC = (CIN > 32) ? 32 : CIN;
    #pragma unroll
    for (int kc = 0; kc < CIN; kc += KC) {
      float x[KC];
      #pragma unroll
      for (int k4 = 0; k4 < KC / 4; ++k4) {
        float4 v = *reinterpret_cast<const float4*>(xrow + kc + k4 * 4);
        x[4*k4+0] = v.x; x[4*k4+1] = v.y; x[4*k4+2] = v.z; x[4*k4+3] = v.w;
      }
      #pragma unroll
      for (int k = 0; k < KC; ++k) {
        #pragma unroll
        for (int jj = 0; jj < JT; ++jj)
          acc[jj] += x[k] * sW[(kc + k) * JT + jj];
      }
    }
  } else {
    #pragma unroll
    for (int k = 0; k < CIN; ++k) {
      float xv = xrow[k];
      #pragma unroll
      for (int jj = 0; jj < JT; ++jj)
        acc[jj] += xv * sW[k * JT + jj];
    }
  }
  float* orow = out + (size_t)node * COUT + j0;
  #pragma unroll
  for (int jj = 0; jj < JT; jj += 4) {
    float4 r; r.x = acc[jj]; r.y = acc[jj+1]; r.z = acc[jj+2]; r.w = acc[jj+3];
    *reinterpret_cast<float4*>(orow + jj) = r;
  }
}

// ---- MLP second half: t=relu(h*scale+shift); out[, j-tile]=leaky(t@W+b) ----
template<int CIN, int COUT, int JT>
__global__ __launch_bounds__(BLK) void mlp2_kernel(const float* __restrict__ h,
    const float* __restrict__ scale, const float* __restrict__ shift,
    const float* __restrict__ W, const float* __restrict__ b,
    float* __restrict__ out, int n) {
  __shared__ float sW[CIN * JT];
  __shared__ float sB[JT];
  __shared__ float sSc[CIN];
  __shared__ float sSh[CIN];
  const int j0 = blockIdx.y * JT;
  for (int i = threadIdx.x; i < CIN * JT; i += BLK) {
    int k = i / JT, jj = i - k * JT;
    sW[i] = W[k * COUT + j0 + jj];
  }
  for (int i = threadIdx.x; i < JT; i += BLK) sB[i] = b[j0 + i];
  for (int i = threadIdx.x; i < CIN; i += BLK) { sSc[i] = scale[i]; sSh[i] = shift[i]; }
  __syncthreads();
  int node = blockIdx.x * BLK + threadIdx.x;
  if (node >= n) return;
  float acc[JT];
  #pragma unroll
  for (int jj = 0; jj < JT; ++jj) acc[jj] = sB[jj];
  const float* xrow = h + (size_t)node * CIN;
  constexpr int KC = (CIN > 32) ? 32 : CIN;
  #pragma unroll
  for (int kc = 0; kc < CIN; kc += KC) {
    float x[KC];
    #pragma unroll
    for (int k4 = 0; k4 < KC / 4; ++k4) {
      float4 v = *reinterpret_cast<const float4*>(xrow + kc + k4 * 4);
      x[4*k4+0] = fmaxf(v.x * sSc[kc+4*k4+0] + sSh[kc+4*k4+0], 0.f);
      x[4*k4+1] = fmaxf(v.y * sSc[kc+4*k4+1] + sSh[kc+4*k4+1], 0.f);
      x[4*k4+2] = fmaxf(v.z * sSc[kc+4*k4+2] + sSh[kc+4*k4+2], 0.f);
      x[4*k4+3] = fmaxf(v.w * sSc[kc+4*k4+3] + sSh[kc+4*k4+3], 0.f);
    }
    #pragma unroll
    for (int k = 0; k < KC; ++k) {
      #pragma unroll
      for (int jj = 0; jj < JT; ++jj)
        acc[jj] += x[k] * sW[(kc + k) * JT + jj];
    }
  }
  float* orow = out + (size_t)node * COUT + j0;
  #pragma unroll
  for (int jj = 0; jj < JT; jj += 4) {
    float a0 = acc[jj], a1 = acc[jj+1], a2 = acc[jj+2], a3 = acc[jj+3];
    a0 = a0 > 0.f ? a0 : F_NEG * a0;
    a1 = a1 > 0.f ? a1 : F_NEG * a1;
    a2 = a2 > 0.f ? a2 : F_NEG * a2;
    a3 = a3 > 0.f ? a3 : F_NEG * a3;
    float4 r; r.x = a0; r.y = a1; r.z = a2; r.w = a3;
    *reinterpret_cast<float4*>(orow + jj) = r;
  }
}

// ---------------- CSR build ----------------
__global__ __launch_bounds__(BLK) void deg_kernel(const int* __restrict__ dst,
    int* __restrict__ deg, int E) {
  int e = blockIdx.x * BLK + threadIdx.x;
  if (e < E) atomicAdd(&deg[dst[e]], 1);
}

__global__ __launch_bounds__(BLK) void blocksum_kernel(const int* __restrict__ deg,
    int* __restrict__ bsum, int n) {
  int i = blockIdx.x * BLK + threadIdx.x;
  int v = (i < n) ? deg[i] : 0;
  for (int off = 32; off; off >>= 1) v += __shfl_down(v, off);
  __shared__ int wsum[4];
  int lane = threadIdx.x & 63, wid = threadIdx.x >> 6;
  if (lane == 0) wsum[wid] = v;
  __syncthreads();
  if (threadIdx.x == 0) bsum[blockIdx.x] = wsum[0] + wsum[1] + wsum[2] + wsum[3];
}

__global__ __launch_bounds__(512) void scanb_kernel(int* __restrict__ bsum, int nb) {
  __shared__ int s[512];
  int t = threadIdx.x;
  int orig = (t < nb) ? bsum[t] : 0;
  s[t] = orig;
  __syncthreads();
  for (int off = 1; off < 512; off <<= 1) {
    int add = (t >= off) ? s[t - off] : 0;
    __syncthreads();
    s[t] += add;
    __syncthreads();
  }
  if (t < nb) bsum[t] = s[t] - orig;   // exclusive
}

__global__ __launch_bounds__(BLK) void rowstart_kernel(const int* __restrict__ deg,
    const int* __restrict__ bsum, int* __restrict__ rowstart,
    int* __restrict__ cursor, int n) {
  __shared__ int s[BLK];
  int t = threadIdx.x, i = blockIdx.x * BLK + t;
  int orig = (i < n) ? deg[i] : 0;
  s[t] = orig;
  __syncthreads();
  for (int off = 1; off < BLK; off <<= 1) {
    int add = (t >= off) ? s[t - off] : 0;
    __syncthreads();
    s[t] += add;
    __syncthreads();
  }
  if (i < n) { int st = bsum[blockIdx.x] + s[t] - orig; rowstart[i] = st; cursor[i] = st; }
}

__global__ __launch_bounds__(BLK) void scatter_kernel(const int* __restrict__ src,
    const int* __restrict__ dst, int* __restrict__ cursor, int* __restrict__ eidx, int E) {
  int e = blockIdx.x * BLK + threadIdx.x;
  if (e >= E) return;
  int p = atomicAdd(&cursor[dst[e]], 1);
  eidx[p] = src[e];
}

// ---- fused gather-aggregate + residual: out = num/(den+1e-16) + x[d] ----
template<int C>
__global__ __launch_bounds__(BLK) void agg_kernel(const int* __restrict__ rowstart,
    const int* __restrict__ deg, const int* __restrict__ eidx,
    const float* __restrict__ x, float* __restrict__ out, int n) {
  int gid = blockIdx.x * BLK + threadIdx.x;
  int node = gid / C;
  int c = gid & (C - 1);
  if (node >= n) return;
  int s0 = rowstart[node];
  int d = deg[node];
  float den = 0.f, num = 0.f;
  int j = 0;
  for (; j + 1 < d; j += 2) {
    int sA = eidx[s0 + j], sB = eidx[s0 + j + 1];
    float xa = x[(size_t)sA * C + c];
    float xb = x[(size_t)sB * C + c];
    float ma = fmaxf(xa, 0.f) + F_EPS;
    float mb = fmaxf(xb, 0.f) + F_EPS;
    float aa = expf(ma), ab = expf(mb);
    den += aa + ab;
    num += ma * aa + mb * ab;
  }
  if (j < d) {
    int sA = eidx[s0 + j];
    float xa = x[(size_t)sA * C + c];
    float ma = fmaxf(xa, 0.f) + F_EPS;
    float aa = expf(ma);
    den += aa;
    num += ma * aa;
  }
  float xd = x[(size_t)node * C + c];
  out[(size_t)node * C + c] = num / (den + 1e-16f) + xd;
}

// ---- BN stats pass 1: per-block f64 partial column sums (NO atomics) ----
template<int COUT>
__global__ __launch_bounds__(BLK) void stat_kernel(const float* __restrict__ h,
    double* __restrict__ partial, int n) {
  constexpr int G = COUT / 4;
  constexpr int REPS = BLK / G;
  double s0 = 0, s1 = 0, s2 = 0, s3 = 0, q0 = 0, q1 = 0, q2 = 0, q3 = 0;
  int total4 = n * G;
  for (int i = blockIdx.x * BLK + threadIdx.x; i < total4; i += gridDim.x * BLK) {
    float4 v = reinterpret_cast<const float4*>(h)[i];
    double dx = v.x, dy = v.y, dz = v.z, dw = v.w;
    s0 += dx; q0 += dx * dx;
    s1 += dy; q1 += dy * dy;
    s2 += dz; q2 += dz * dz;
    s3 += dw; q3 += dw * dw;
  }
  __shared__ double sL[BLK * 8];
  double* my = sL + threadIdx.x * 8;
  my[0] = s0; my[1] = s1; my[2] = s2; my[3] = s3;
  my[4] = q0; my[5] = q1; my[6] = q2; my[7] = q3;
  __syncthreads();
  int g = threadIdx.x;
  if (g < G) {
    for (int r = 1; r < REPS; ++r) {
      double* o = sL + (g + r * G) * 8;
      s0 += o[0]; s1 += o[1]; s2 += o[2]; s3 += o[3];
      q0 += o[4]; q1 += o[5]; q2 += o[6]; q3 += o[7];
    }
    double* prow = partial + (size_t)blockIdx.x * (2 * COUT);
    prow[4*g+0] = s0; prow[4*g+1] = s1; prow[4*g+2] = s2; prow[4*g+3] = s3;
    prow[COUT+4*g+0] = q0; prow[COUT+4*g+1] = q1;
    prow[COUT+4*g+2] = q2; prow[COUT+4*g+3] = q3;
  }
}

// ---- BN stats pass 2: one block per channel reduces STATNB partials ----
template<int COUT>
__global__ __launch_bounds__(256) void bn_fin2(const double* __restrict__ partial,
    const float* __restrict__ g, const float* __restrict__ be,
    float* __restrict__ sc, float* __restrict__ sh, int n) {
  int j = blockIdx.x;
  int t = threadIdx.x;
  double s = 0, q = 0;
  for (int b = t; b < STATNB; b += 256) {
    const double* prow = partial + (size_t)b * (2 * COUT);
    s += prow[j];
    q += prow[COUT + j];
  }
  for (int off = 32; off; off >>= 1) { s += __shfl_down(s, off); q += __shfl_down(q, off); }
  __shared__ double sw[4][2];
  int lane = t & 63, wid = t >> 6;
  if (lane == 0) { sw[wid][0] = s; sw[wid][1] = q; }
  __syncthreads();
  if (t == 0) {
    s = sw[0][0] + sw[1][0] + sw[2][0] + sw[3][0];
    q = sw[0][1] + sw[1][1] + sw[2][1] + sw[3][1];
    double inv_n = 1.0 / (double)n;
    double mu = s * inv_n;
    double var = q * inv_n - mu * mu;
    double scd = (double)g[j] / sqrt(var + 1e-5);
    sc[j] = (float)scd;
    sh[j] = (float)((double)be[j] - mu * scd);
  }
}

// ---- score + key + round-0 histogram (byte 7) ----
__global__ __launch_bounds__(BLK) void score_kernel(const float* __restrict__ x,
    const float* __restrict__ w, float* __restrict__ scores,
    u64* __restrict__ keys, int* __restrict__ ghist, int n) {
  __shared__ float sw[64];
  __shared__ float snorm;
  __shared__ int hl[256];
  if (threadIdx.x < 64) sw[threadIdx.x] = w[threadIdx.x];
  hl[threadIdx.x] = 0;
  __syncthreads();
  if (threadIdx.x < 64) {
    float v = sw[threadIdx.x];
    float sq = v * v;
    for (int off = 32; off; off >>= 1) sq += __shfl_down(sq, off);
    if (threadIdx.x == 0) snorm = 1.f / sqrtf(sq);
  }
  __syncthreads();
  int node = blockIdx.x * BLK + threadIdx.x;
  if (node < n) {
    const float4* row = reinterpret_cast<const float4*>(x + (size_t)node * 64);
    float acc = 0.f;
    #pragma unroll
    for (int k4 = 0; k4 < 16; ++k4) {
      float4 v = row[k4];
      const float4 wv = *reinterpret_cast<const float4*>(&sw[4 * k4]);
      acc += v.x * wv.x + v.y * wv.y + v.z * wv.z + v.w * wv.w;
    }
    float s = tanhf(acc * snorm);
    scores[node] = s;
    u64 key = ((u64)ord_f32(s) << 32) | (unsigned int)(~node);
    keys[node] = key;
    atomicAdd(&hl[(int)(key >> 56)], 1);
  }
  __syncthreads();
  int v = hl[threadIdx.x];
  if (v) atomicAdd(&ghist[threadIdx.x], v);
}

// istate: [0]=k remaining [1]=digit [2]=sel count [4]=out count
__global__ void pick0_kernel(int* __restrict__ istate, const int* __restrict__ hist) {
  if (threadIdx.x == 0) {
    int k = TOPK, run = 0;
    for (int d = 255; d >= 0; --d) {
      int c = hist[d];
      if (run + c >= k) { istate[1] = d; istate[0] = k - run; break; }
      run += c;
    }
    istate[2] = 0; istate[4] = 0;
  }
}

__global__ __launch_bounds__(BLK) void compact0_kernel(const u64* __restrict__ in,
    u64* __restrict__ outb, u64* __restrict__ sel, int* __restrict__ istate, int n) {
  int i = blockIdx.x * BLK + threadIdx.x;
  if (i >= n) return;
  u64 kkey = in[i];
  int b = (int)(kkey >> 56);
  int digit = istate[1];
  if (b > digit) {
    sel[atomicAdd(&istate[2], 1)] = kkey;
  } else if (b == digit) {
    outb[atomicAdd(&istate[4], 1)] = kkey;
  }
}

// ---- single block: radix rounds 1..7 + append + bitonic sort + gather ----
__global__ __launch_bounds__(1024) void topk_finish(u64* __restrict__ bufB,
    u64* __restrict__ bufA, u64* __restrict__ sel, const int* __restrict__ istate,
    const float* __restrict__ scores, const float* __restrict__ x,
    float* __restrict__ out) {
  __shared__ int hl[256];
  __shared__ int sh_digit, sh_k, sh_sel, sh_out, sh_cnt;
  __shared__ u64 sk[512];
  int t = threadIdx.x;
  if (t == 0) { sh_cnt = istate[4]; sh_k = istate[0]; sh_sel = istate[2]; }
  __syncthreads();
  u64* cur = bufB;
  u64* nxt = bufA;
  for (int shift = 48; shift >= 0; shift -= 8) {
    for (int i = t; i < 256; i += 1024) hl[i] = 0;
    __syncthreads();
    int cnt = sh_cnt;
    for (int i = t; i < cnt; i += 1024) atomicAdd(&hl[(int)((cur[i] >> shift) & 255ull)], 1);
    __syncthreads();
    if (t == 0) {
      int k = sh_k, run = 0;
      for (int d = 255; d >= 0; --d) {
        int c = hl[d];
        if (run + c >= k) { sh_digit = d; sh_k = k - run; break; }
        run += c;
      }
      sh_out = 0;
    }
    __syncthreads();
    int digit = sh_digit;
    for (int i = t; i < cnt; i += 1024) {
      u64 kk = cur[i];
      int b = (int)((kk >> shift) & 255ull);
      if (b > digit) sel[atomicAdd(&sh_sel, 1)] = kk;
      else if (b == digit) nxt[atomicAdd(&sh_out, 1)] = kk;
    }
    __syncthreads();
    if (t == 0) sh_cnt = sh_out;
    __syncthreads();
    u64* tmp = cur; cur = nxt; nxt = tmp;
  }
  int base = sh_sel, krem = sh_k;
  for (int i = t; i < krem; i += 1024) sel[base + i] = cur[i];
  __syncthreads();
  if (t < 512) sk[t] = sel[t];
  __syncthreads();
  for (int k = 2; k <= 512; k <<= 1) {
    for (int j = k >> 1; j > 0; j >>= 1) {
      if (t < 512) {
        int ixj = t ^ j;
        if (ixj > t) {
          bool dirDesc = ((t & k) == 0);
          u64 A = sk[t], B = sk[ixj];
          bool swp = dirDesc ? (A < B) : (A > B);
          if (swp) { sk[t] = B; sk[ixj] = A; }
        }
      }
      __syncthreads();
    }
  }
  for (int i = t; i < 512 * 16; i += 1024) {
    int r = i >> 4, c = i & 15;
    u64 kk = sk[r];
    int nidx = (int)(~(unsigned int)(kk & 0xffffffffull));
    float v = scores[nidx];
    float4 xv = reinterpret_cast<const float4*>(x)[(size_t)nidx * 16 + c];
    float4 r4; r4.x = xv.x * v; r4.y = xv.y * v; r4.z = xv.z * v; r4.w = xv.w * v;
    reinterpret_cast<float4*>(out)[(size_t)r * 16 + c] = r4;
  }
}

extern "C" void kernel_launch(void* const* d_in, const int* in_sizes, int n_in,
                              void* d_out, int out_size, void* d_ws, size_t ws_size,
                              hipStream_t stream) {
  const int N = in_sizes[0] / 3;
  const int E = in_sizes[1] / 2;

  const float* pos   = (const float*)d_in[0];
  const int*   ei    = (const int*)d_in[1];
  const int*   src   = ei;
  const int*   dst   = ei + E;
  const float* c1_lw = (const float*)d_in[2];
  const float* c1_lb = (const float*)d_in[3];
  const float* c1_w1 = (const float*)d_in[4];
  const float* c1_b1 = (const float*)d_in[5];
  const float* c1_g1 = (const float*)d_in[6];
  const float* c1_be1= (const float*)d_in[7];
  const float* c1_w2 = (const float*)d_in[8];
  const float* c1_b2 = (const float*)d_in[9];
  const float* c2_lw = (const float*)d_in[10];
  const float* c2_lb = (const float*)d_in[11];
  const float* c2_w1 = (const float*)d_in[12];
  const float* c2_b1 = (const float*)d_in[13];
  const float* c2_g1 = (const float*)d_in[14];
  const float* c2_be1= (const float*)d_in[15];
  const float* c2_w2 = (const float*)d_in[16];
  const float* c2_b2 = (const float*)d_in[17];
  const float* poolw = (const float*)d_in[18];

  // ---- workspace layout ----
  float* ws = (float*)d_ws;
  float* x1   = ws;                         // 16N
  float* h1   = ws + (size_t)16 * N;        // 32N
  float* o1   = ws + (size_t)48 * N;        // 16N
  float* res2 = ws;                         // 64N (after x1/h1/o1 dead)
  float* x2   = ws + (size_t)64 * N;        // 64N (res1 uses this region first)
  float* res1 = x2;                         // 16N (dead before lin<16,64> writes x2)
  float* h2   = ws + (size_t)128 * N;       // 128N
  float* o2   = ws + (size_t)256 * N;       // 64N
  float* scores = ws + (size_t)320 * N;     // N
  u64* candA = (u64*)(ws + (size_t)321 * N);            // N
  u64* candB = candA + N;                               // N
  u64* sel   = candB + N;                               // 512
  double* partial = (double*)(sel + TOPK);              // STATNB * 256 doubles (2 MB)
  int* ibase   = (int*)(partial + (size_t)STATNB * 256);
  int* istate  = ibase;            // 8
  int* hist    = ibase + 8;        // 256
  int* bsum    = ibase + 264;      // 512
  int* deg     = ibase + 776;      // N
  int* rowstart= deg + N;          // N
  int* cursor  = rowstart + N;     // N
  int* eidx    = cursor + N;       // E
  float* fsc   = (float*)(eidx + E);
  float* sc1 = fsc;        float* sh1 = fsc + 32;
  float* sc2 = fsc + 64;   float* sh2 = fsc + 192;     // 320 floats total

  const int nbN = (N + BLK - 1) / BLK;
  const int nbE = (E + BLK - 1) / BLK;

  // replay-safe zeroing: only deg + hist need it (atomic accumulation targets)
  hipMemsetAsync(deg, 0, (size_t)N * sizeof(int), stream);
  hipMemsetAsync(hist, 0, 256 * sizeof(int), stream);

  // ---- CSR build (shared by both convs) ----
  deg_kernel<<<nbE, BLK, 0, stream>>>(dst, deg, E);
  blocksum_kernel<<<nbN, BLK, 0, stream>>>(deg, bsum, N);
  scanb_kernel<<<1, 512, 0, stream>>>(bsum, nbN);
  rowstart_kernel<<<nbN, BLK, 0, stream>>>(deg, bsum, rowstart, cursor, N);
  scatter_kernel<<<nbE, BLK, 0, stream>>>(src, dst, cursor, eidx, E);

  // ---- conv1 ----
  lin_kernel<3, 16, 16><<<dim3(nbN, 1), BLK, 0, stream>>>(pos, c1_lw, c1_lb, x1, N);
  agg_kernel<16><<<(N * 16 + BLK - 1) / BLK, BLK, 0, stream>>>(rowstart, deg, eidx, x1, res1, N);
  lin_kernel<16, 32, 32><<<dim3(nbN, 1), BLK, 0, stream>>>(res1, c1_w1, c1_b1, h1, N);
  stat_kernel<32><<<STATNB, BLK, 0, stream>>>(h1, partial, N);
  bn_fin2<32><<<32, 256, 0, stream>>>(partial, c1_g1, c1_be1, sc1, sh1, N);
  mlp2_kernel<32, 16, 16><<<dim3(nbN, 1), BLK, 0, stream>>>(h1, sc1, sh1, c1_w2, c1_b2, o1, N);

  // ---- conv2 ----
  lin_kernel<16, 64, 16><<<dim3(nbN, 4), BLK, 0, stream>>>(o1, c2_lw, c2_lb, x2, N);
  agg_kernel<64><<<(N * 64 + BLK - 1) / BLK, BLK, 0, stream>>>(rowstart, deg, eidx, x2, res2, N);
  lin_kernel<64, 128, 16><<<dim3(nbN, 8), BLK, 0, stream>>>(res2, c2_w1, c2_b1, h2, N);
  stat_kernel<128><<<STATNB, BLK, 0, stream>>>(h2, partial, N);
  bn_fin2<128><<<128, 256, 0, stream>>>(partial, c2_g1, c2_be1, sc2, sh2, N);
  mlp2_kernel<128, 64, 16><<<dim3(nbN, 4), BLK, 0, stream>>>(h2, sc2, sh2, c2_w2, c2_b2, o2, N);

  // ---- scores + exact top-K ----
  score_kernel<<<nbN, BLK, 0, stream>>>(o2, poolw, scores, candA, hist, N);
  pick0_kernel<<<1, 64, 0, stream>>>(istate, hist);
  compact0_kernel<<<nbN, BLK, 0, stream>>>(candA, candB, sel, istate, N);
  topk_finish<<<1, 1024, 0, stream>>>(candB, candA, sel, istate, scores, o2, (float*)d_out);

  (void)n_in; (void)out_size; (void)ws_size;
}